// Round 1
// baseline (229.478 us; speedup 1.0000x reference)
//
#include <hip/hip_runtime.h>
#include <hip/hip_bf16.h>

// KAN layer = GEMM: out[b,o] = sum_{i,k} T_k(tanh(x[b,i])) * W[o,i,k] + bias[o]
//   A (basis) : [4096, 8192] bf16 (built in ws)
//   B (weights): [1024, 8192] bf16 (converted in ws)  -> gemm_bt
// Dims
#define MD 4096
#define ND 1024
#define KD 8192
#define IN_F 1024
#define KB 8  // basis dim

typedef __bf16 bf16x8 __attribute__((ext_vector_type(8)));
typedef float f32x4 __attribute__((ext_vector_type(4)));

// ---------------- Pass 1: basis = Chebyshev(tanh(x)) -> bf16 ----------------
__global__ __launch_bounds__(256) void basis_kernel(
    const float* __restrict__ x, __bf16* __restrict__ A, int n) {
  int i = blockIdx.x * blockDim.x + threadIdx.x;
  if (i >= n) return;
  float t = tanhf(x[i]);
  float two_t = 2.0f * t;
  float T0 = 1.0f;
  float T1 = t;
  float T2 = two_t * T1 - T0;
  float T3 = two_t * T2 - T1;
  float T4 = two_t * T3 - T2;
  float T5 = two_t * T4 - T3;
  float T6 = two_t * T5 - T4;
  float T7 = two_t * T6 - T5;
  bf16x8 v;
  v[0] = (__bf16)T0; v[1] = (__bf16)T1; v[2] = (__bf16)T2; v[3] = (__bf16)T3;
  v[4] = (__bf16)T4; v[5] = (__bf16)T5; v[6] = (__bf16)T6; v[7] = (__bf16)T7;
  *(bf16x8*)(A + (size_t)i * 8) = v;  // 16B store, k contiguous
}

// ---------------- Pass 2: W fp32 -> bf16 ----------------
__global__ __launch_bounds__(256) void convert_kernel(
    const float* __restrict__ w, __bf16* __restrict__ B, int n8) {
  int i = blockIdx.x * blockDim.x + threadIdx.x;
  if (i >= n8) return;
  const float4* p = (const float4*)(w + (size_t)i * 8);
  float4 a = p[0], b = p[1];
  bf16x8 v;
  v[0] = (__bf16)a.x; v[1] = (__bf16)a.y; v[2] = (__bf16)a.z; v[3] = (__bf16)a.w;
  v[4] = (__bf16)b.x; v[5] = (__bf16)b.y; v[6] = (__bf16)b.z; v[7] = (__bf16)b.w;
  *(bf16x8*)(B + (size_t)i * 8) = v;
}

// ---------------- Pass 3: GEMM_BT + bias ----------------
// BM=64, BN=128, BK=64; 256 threads = 4 waves (2x2), wave tile 32x64 (2x4 of 16x16)
#define BM 64
#define BN 128
#define BK 64

__global__ __launch_bounds__(256) void gemm_bias(
    const __bf16* __restrict__ A, const __bf16* __restrict__ B,
    const float* __restrict__ bias, float* __restrict__ C) {
  __shared__ __align__(16) __bf16 As[BM * BK];
  __shared__ __align__(16) __bf16 Bs[BN * BK];

  const int tid = threadIdx.x;
  const int wave = tid >> 6;
  const int lane = tid & 63;
  const int n0 = blockIdx.x * BN;
  const int m0 = blockIdx.y * BM;
  const int wm = wave >> 1;   // 0..1
  const int wn = wave & 1;    // 0..1

  // ---- staging (global_load_lds, 16B/lane; LDS dst = uniform base + lane*16)
  const int ar = lane >> 3;        // row 0..7 within 8-row group
  const int ac = (lane & 7) * 8;   // 8-elem col group
  const __bf16* gA = A + (size_t)(m0 + wave * 16 + ar) * KD + ac;
  const __bf16* gB = B + (size_t)(n0 + wave * 32 + ar) * KD + ac;
  const __bf16* lA = As + (wave * 16) * BK;
  const __bf16* lB = Bs + (wave * 32) * BK;

  f32x4 acc[2][4];
#pragma unroll
  for (int i = 0; i < 2; i++)
#pragma unroll
    for (int j = 0; j < 4; j++) acc[i][j] = (f32x4){0.f, 0.f, 0.f, 0.f};

  // ---- fragment read coords (16x16x32 layout: m=lane&15, k=(lane>>4)*8+j)
  const int fr = lane & 15;
  const int fk = (lane >> 4) * 8;

  for (int kt = 0; kt < KD; kt += BK) {
    // stage A: 64 rows, 16/wave, 8/instr
#pragma unroll
    for (int j = 0; j < 2; j++)
      __builtin_amdgcn_global_load_lds(
          (const __attribute__((address_space(1))) void*)(gA + kt + (size_t)j * 8 * KD),
          (__attribute__((address_space(3))) void*)(lA + j * 8 * BK), 16, 0, 0);
    // stage B: 128 rows, 32/wave, 8/instr
#pragma unroll
    for (int j = 0; j < 4; j++)
      __builtin_amdgcn_global_load_lds(
          (const __attribute__((address_space(1))) void*)(gB + kt + (size_t)j * 8 * KD),
          (__attribute__((address_space(3))) void*)(lB + j * 8 * BK), 16, 0, 0);
    __syncthreads();

#pragma unroll
    for (int s = 0; s < 2; s++) {
      bf16x8 af[2], bfr[4];
#pragma unroll
      for (int mi = 0; mi < 2; mi++)
        af[mi] = *(const bf16x8*)&As[(wm * 32 + mi * 16 + fr) * BK + s * 32 + fk];
#pragma unroll
      for (int ni = 0; ni < 4; ni++)
        bfr[ni] = *(const bf16x8*)&Bs[(wn * 64 + ni * 16 + fr) * BK + s * 32 + fk];
#pragma unroll
      for (int mi = 0; mi < 2; mi++)
#pragma unroll
        for (int ni = 0; ni < 4; ni++)
          acc[mi][ni] = __builtin_amdgcn_mfma_f32_16x16x32_bf16(
              af[mi], bfr[ni], acc[mi][ni], 0, 0, 0);
    }
    __syncthreads();
  }

  // ---- epilogue: C/D layout col=lane&15, row=(lane>>4)*4+r ; add bias
  const int col0 = n0 + wn * 64;
  const int row0 = m0 + wm * 32 + (lane >> 4) * 4;
#pragma unroll
  for (int ni = 0; ni < 4; ni++) {
    int col = col0 + ni * 16 + (lane & 15);
    float bv = bias[col];
#pragma unroll
    for (int mi = 0; mi < 2; mi++) {
      int row = row0 + mi * 16;
#pragma unroll
      for (int r = 0; r < 4; r++)
        C[(size_t)(row + r) * ND + col] = acc[mi][ni][r] + bv;
    }
  }
}

extern "C" void kernel_launch(void* const* d_in, const int* in_sizes, int n_in,
                              void* d_out, int out_size, void* d_ws, size_t ws_size,
                              hipStream_t stream) {
  const float* x = (const float*)d_in[0];     // [4096,1024]
  const float* w = (const float*)d_in[1];     // [1024,1024,8]
  const float* bias = (const float*)d_in[2];  // [1024]
  float* out = (float*)d_out;                 // [4096,1024]

  __bf16* Abf = (__bf16*)d_ws;  // 4096*8192 bf16 = 64 MB
  __bf16* Bbf = (__bf16*)((char*)d_ws + (size_t)MD * KD * 2);  // 1024*8192 bf16 = 16 MB

  {  // pass 1: basis
    int n = MD * IN_F;  // 4.2M elements, each expands to 8 bf16
    basis_kernel<<<(n + 255) / 256, 256, 0, stream>>>(x, Abf, n);
  }
  {  // pass 2: weight convert (8 floats / thread)
    int n8 = (ND * KD) / 8;
    convert_kernel<<<(n8 + 255) / 256, 256, 0, stream>>>(w, Bbf, n8);
  }
  {  // pass 3: GEMM + bias
    dim3 grid(ND / BN, MD / BM);  // (8, 64) = 512 blocks -> 2 blocks/CU
    gemm_bias<<<grid, 256, 0, stream>>>(Abf, Bbf, bias, out);
  }
}

// Round 2
// 200.303 us; speedup vs baseline: 1.1457x; 1.1457x over previous
//
#include <hip/hip_runtime.h>
#include <hip/hip_bf16.h>

// KAN layer = GEMM: out[b,o] = sum_{i,k} T_k(tanh(x[b,i])) * W[o,i,k] + bias[o]
//   A (basis) : [4096, 8192] bf16 (built in ws)
//   B (weights): [1024, 8192] bf16 (converted in ws)  -> gemm_bt
#define MD 4096
#define ND 1024
#define KD 8192
#define IN_F 1024

typedef __bf16 bf16x8 __attribute__((ext_vector_type(8)));
typedef float f32x4 __attribute__((ext_vector_type(4)));

// ---------------- Pass 1 (merged): basis + W convert ----------------
// First N_BASIS threads: one x element -> 8 Chebyshev bf16.
// Next  N_CONV  threads: 8 fp32 W -> 8 bf16.
#define N_BASIS (MD * IN_F)
#define N_CONV ((ND * KD) / 8)

__global__ __launch_bounds__(256) void prep_kernel(
    const float* __restrict__ x, const float* __restrict__ w,
    __bf16* __restrict__ A, __bf16* __restrict__ B) {
  int i = blockIdx.x * blockDim.x + threadIdx.x;
  if (i < N_BASIS) {
    float t = tanhf(x[i]);
    float two_t = 2.0f * t;
    float T0 = 1.0f;
    float T1 = t;
    float T2 = two_t * T1 - T0;
    float T3 = two_t * T2 - T1;
    float T4 = two_t * T3 - T2;
    float T5 = two_t * T4 - T3;
    float T6 = two_t * T5 - T4;
    float T7 = two_t * T6 - T5;
    bf16x8 v;
    v[0] = (__bf16)T0; v[1] = (__bf16)T1; v[2] = (__bf16)T2; v[3] = (__bf16)T3;
    v[4] = (__bf16)T4; v[5] = (__bf16)T5; v[6] = (__bf16)T6; v[7] = (__bf16)T7;
    *(bf16x8*)(A + (size_t)i * 8) = v;
  } else if (i < N_BASIS + N_CONV) {
    int j = i - N_BASIS;
    const float4* p = (const float4*)(w + (size_t)j * 8);
    float4 a = p[0], b = p[1];
    bf16x8 v;
    v[0] = (__bf16)a.x; v[1] = (__bf16)a.y; v[2] = (__bf16)a.z; v[3] = (__bf16)a.w;
    v[4] = (__bf16)b.x; v[5] = (__bf16)b.y; v[6] = (__bf16)b.z; v[7] = (__bf16)b.w;
    *(bf16x8*)(B + (size_t)j * 8) = v;
  }
}

// ---------------- Pass 2: GEMM_BT + bias ----------------
// BM=64, BN=128, BK=64; 256 threads = 4 waves (2x2), wave tile 32x64 (2x4 of 16x16).
// LDS XOR swizzle: logical 16B group g of row r lives at physical group g^(r&7).
// Swizzle applied on the GLOBAL address side during staging (global_load_lds
// forces LDS dst = base + lane*16), and on the index side during fragment reads.
#define BM 64
#define BN 128
#define BK 64

__global__ __launch_bounds__(256) void gemm_bias(
    const __bf16* __restrict__ A, const __bf16* __restrict__ B,
    const float* __restrict__ bias, float* __restrict__ C) {
  __shared__ __align__(16) __bf16 As[BM * BK];
  __shared__ __align__(16) __bf16 Bs[BN * BK];

  const int tid = threadIdx.x;
  const int wave = tid >> 6;
  const int lane = tid & 63;
  const int n0 = blockIdx.x * BN;
  const int m0 = blockIdx.y * BM;
  const int wm = wave >> 1;   // 0..1
  const int wn = wave & 1;    // 0..1

  // ---- staging: one global_load_lds (16B/lane) covers 8 rows of 128B.
  // lane -> row ar = lane>>3 (r&7 == ar), physical group pg = lane&7.
  // Physical slot (r,pg) must hold logical group pg^ar -> load that column.
  const int ar = lane >> 3;                  // 0..7
  const int swz_col = ((lane & 7) ^ ar) * 8; // swizzled 8-elem column group
  const __bf16* gA = A + (size_t)(m0 + wave * 16 + ar) * KD + swz_col;
  const __bf16* gB = B + (size_t)(n0 + wave * 32 + ar) * KD + swz_col;
  const __bf16* lA = As + (wave * 16) * BK;
  const __bf16* lB = Bs + (wave * 32) * BK;

  f32x4 acc[2][4];
#pragma unroll
  for (int i = 0; i < 2; i++)
#pragma unroll
    for (int j = 0; j < 4; j++) acc[i][j] = (f32x4){0.f, 0.f, 0.f, 0.f};

  // ---- fragment coords (16x16x32: m=lane&15, k=(lane>>4)*8+j)
  const int fr = lane & 15;
  const int fr7 = fr & 7;
  const int qk = lane >> 4;  // 0..3

  for (int kt = 0; kt < KD; kt += BK) {
#pragma unroll
    for (int j = 0; j < 2; j++)
      __builtin_amdgcn_global_load_lds(
          (const __attribute__((address_space(1))) void*)(gA + kt + (size_t)j * 8 * KD),
          (__attribute__((address_space(3))) void*)(lA + j * 8 * BK), 16, 0, 0);
#pragma unroll
    for (int j = 0; j < 4; j++)
      __builtin_amdgcn_global_load_lds(
          (const __attribute__((address_space(1))) void*)(gB + kt + (size_t)j * 8 * KD),
          (__attribute__((address_space(3))) void*)(lB + j * 8 * BK), 16, 0, 0);
    __syncthreads();

#pragma unroll
    for (int s = 0; s < 2; s++) {
      // logical 16B group gl = s*4 + qk; physical = gl ^ (row&7) = gl ^ fr7
      const int pa = ((s * 4 + qk) ^ fr7) * 8;
      bf16x8 af[2], bfr[4];
#pragma unroll
      for (int mi = 0; mi < 2; mi++)
        af[mi] = *(const bf16x8*)&As[(wm * 32 + mi * 16 + fr) * BK + pa];
#pragma unroll
      for (int ni = 0; ni < 4; ni++)
        bfr[ni] = *(const bf16x8*)&Bs[(wn * 64 + ni * 16 + fr) * BK + pa];
#pragma unroll
      for (int mi = 0; mi < 2; mi++)
#pragma unroll
        for (int ni = 0; ni < 4; ni++)
          acc[mi][ni] = __builtin_amdgcn_mfma_f32_16x16x32_bf16(
              af[mi], bfr[ni], acc[mi][ni], 0, 0, 0);
    }
    __syncthreads();
  }

  // ---- epilogue: C/D layout col=lane&15, row=(lane>>4)*4+r ; add bias
  const int col0 = n0 + wn * 64;
  const int row0 = m0 + wm * 32 + (lane >> 4) * 4;
#pragma unroll
  for (int ni = 0; ni < 4; ni++) {
    int col = col0 + ni * 16 + (lane & 15);
    float bv = bias[col];
#pragma unroll
    for (int mi = 0; mi < 2; mi++) {
      int row = row0 + mi * 16;
#pragma unroll
      for (int r = 0; r < 4; r++)
        C[(size_t)(row + r) * ND + col] = acc[mi][ni][r] + bv;
    }
  }
}

extern "C" void kernel_launch(void* const* d_in, const int* in_sizes, int n_in,
                              void* d_out, int out_size, void* d_ws, size_t ws_size,
                              hipStream_t stream) {
  const float* x = (const float*)d_in[0];     // [4096,1024]
  const float* w = (const float*)d_in[1];     // [1024,1024,8]
  const float* bias = (const float*)d_in[2];  // [1024]
  float* out = (float*)d_out;                 // [4096,1024]

  __bf16* Abf = (__bf16*)d_ws;  // 4096*8192 bf16 = 64 MB
  __bf16* Bbf = (__bf16*)((char*)d_ws + (size_t)MD * KD * 2);  // 16 MB

  {  // merged basis + convert
    int n = N_BASIS + N_CONV;
    prep_kernel<<<(n + 255) / 256, 256, 0, stream>>>(x, w, Abf, Bbf);
  }
  {  // GEMM + bias
    dim3 grid(ND / BN, MD / BM);  // (8, 64) = 512 blocks -> 2 blocks/CU
    gemm_bias<<<grid, 256, 0, stream>>>(Abf, Bbf, bias, out);
  }
}